// Round 1
// baseline (580.751 us; speedup 1.0000x reference)
//
#include <hip/hip_runtime.h>
#include <math.h>

#define A_ANG 400
#define DDET  512
#define NVOL  256
#define CCH   32
#define KSZ   11
#define PI_F  3.14159265358979323846f

#define NCHUNK 4
#define APC (A_ANG / NCHUNK)   // 100 angles per block

// ---------------------------------------------------------------------------
// K1: causal detector conv: y[a][c][d] = b[c] + sum_k w[c][k] * x[a][d+k-10]
// ---------------------------------------------------------------------------
__global__ __launch_bounds__(256) void k_detconv(const float* __restrict__ x,
                                                 const float* __restrict__ wdet,
                                                 const float* __restrict__ bdet,
                                                 float* __restrict__ y) {
  int idx = blockIdx.x * 256 + threadIdx.x;  // = a*16384 + c*512 + d
  int d = idx & 511;
  int c = (idx >> 9) & 31;   // wave-uniform (64 | 512)
  int a = idx >> 14;
  const float* xr = x + a * DDET;
  float acc = bdet[c];
#pragma unroll
  for (int k = 0; k < KSZ; ++k) {
    int dd = d + k - (KSZ - 1);
    float xv = (dd >= 0) ? xr[dd] : 0.0f;
    acc = fmaf(wdet[c * KSZ + k], xv, acc);
  }
  y[idx] = acc;
}

// ---------------------------------------------------------------------------
// K2: backprojection, v2: latency-bound fix.
//   - grid 1024 = 256 pixel tiles x 4 angle chunks (100 angles each)
//     -> 4 blocks/CU, 16 waves/CU (was 1 block/CU, 11.9% occupancy).
//   - partial sums atomicAdd'ed into vol (zeroed via hipMemsetAsync).
//   - double-buffered LDS window, ONE barrier per angle (was two):
//       issue loads(a+1) -> compute(a) from buf[cur] -> write regs to buf[nxt]
//   - pair-interleaved LDS layout [c/2][cell][2]: taps for a channel pair are
//     two aligned ds_read_b64 (bank = 2*off mod 32; off-span < 23 ->
//     <=2 addrs/bank, conflict-free per m136).
// Window always interior: u in [74.5, 436.5], base in [69,409] -> no masks.
// ---------------------------------------------------------------------------
__global__ __launch_bounds__(256) void k_backproj(const float* __restrict__ y,
                                                  float* __restrict__ vol) {
  __shared__ float s_sin[APC];
  __shared__ float s_cos[APC];
  __shared__ __align__(16) float buf[2][CCH * 32];  // paired layout, 2 x 4KB

  int t = threadIdx.x;
  int tile = blockIdx.x & 255;
  int chunk = blockIdx.x >> 8;
  int a0 = chunk * APC;

  for (int a = t; a < APC; a += 256) {
    float ph = ((float)(a0 + a) + 0.5f) * (PI_F / (float)A_ANG);
    float sv, cv;
    sincosf(ph, &sv, &cv);
    s_sin[a] = sv;
    s_cos[a] = cv;
  }

  int bi = tile >> 4, bj = tile & 15;
  int il = t >> 4, jl = t & 15;
  int i = bi * 16 + il, j = bj * 16 + jl;

  // u = Xp*sin + Yp*cos + 255.5 ; Xp = 127.5 - i ; Yp = j - 127.5
  float Xp = 127.5f - (float)i;
  float Yp = (float)j - 127.5f;
  float Xc = 120.0f - (float)(bi * 16);  // tile-center coords
  float Yc = (float)(bj * 16) - 120.0f;

  // Staging map: LDS float slot e = r*256 + t holds value (c, cell) with
  //   cell = (t>>1)&31,  c = r*8 + ((t>>6)<<1) + (t&1)
  // i.e. value(c,cell) lives at (c>>1)*64 + cell*2 + (c&1)  (pair-interleave).
  int cell_s = (t >> 1) & 31;
  int cpar = ((t >> 6) << 1) | (t & 1);

  float acc[CCH];
#pragma unroll
  for (int c = 0; c < CCH; ++c) acc[c] = 0.0f;

  __syncthreads();  // sin/cos table ready

  // prologue: stage angle 0 into buf[0]
  {
    float sp = s_sin[0], cp = s_cos[0];
    float uc = fmaf(Xc, sp, fmaf(Yc, cp, 255.5f));
    int base = (int)floorf(uc) - 16;
    const float* src = y + (size_t)a0 * (CCH * DDET) + base + cell_s + cpar * DDET;
#pragma unroll
    for (int r = 0; r < 4; ++r) buf[0][r * 256 + t] = src[r * 8 * DDET];
  }
  __syncthreads();

  for (int k = 0; k < APC; ++k) {
    int cur = k & 1;
    int nxt = cur ^ 1;

    // issue next-angle global loads early (latency hides under compute)
    float stg[4];
    bool have = (k + 1 < APC);
    if (have) {
      float spn = s_sin[k + 1], cpn = s_cos[k + 1];
      float ucn = fmaf(Xc, spn, fmaf(Yc, cpn, 255.5f));
      int basen = (int)floorf(ucn) - 16;
      const float* src =
          y + (size_t)(a0 + k + 1) * (CCH * DDET) + basen + cell_s + cpar * DDET;
#pragma unroll
      for (int r = 0; r < 4; ++r) stg[r] = src[r * 8 * DDET];
    }

    // compute angle k from buf[cur]
    {
      float sp = s_sin[k], cp = s_cos[k];
      float uc = fmaf(Xc, sp, fmaf(Yc, cp, 255.5f));
      int base = (int)floorf(uc) - 16;
      float u = fmaf(Xp, sp, fmaf(Yp, cp, 255.5f));
      float k0f = floorf(u);
      float w = u - k0f;
      int off = (int)k0f - base;
      off = max(0, min(30, off));  // provably in [4,28]; clamp for safety
      float w0 = 1.0f - w;
      const float* bp = &buf[cur][2 * off];
#pragma unroll
      for (int c2 = 0; c2 < 16; ++c2) {
        float2 g0 = *(const float2*)(bp + 64 * c2);      // (c even, c odd) @ off
        float2 g1 = *(const float2*)(bp + 64 * c2 + 2);  // @ off+1
        acc[2 * c2 + 0] = fmaf(g0.x, w0, acc[2 * c2 + 0]);
        acc[2 * c2 + 1] = fmaf(g0.y, w0, acc[2 * c2 + 1]);
        acc[2 * c2 + 0] = fmaf(g1.x, w, acc[2 * c2 + 0]);
        acc[2 * c2 + 1] = fmaf(g1.y, w, acc[2 * c2 + 1]);
      }
    }

    // write staged regs into the other buffer (vmcnt wait auto-inserted)
    if (have) {
#pragma unroll
      for (int r = 0; r < 4; ++r) buf[nxt][r * 256 + t] = stg[r];
    }
    __syncthreads();  // reads of cur done + nxt visible: one barrier per angle
  }

  const float DPHI = PI_F / (float)A_ANG;
  float* vp = vol + (size_t)(i * NVOL + j) * CCH;
#pragma unroll
  for (int c = 0; c < CCH; ++c) atomicAdd(vp + c, acc[c] * DPHI);
}

// ---------------------------------------------------------------------------
// K3: 3x3 causal conv 32->32 + sigmoid.  in/out channel-last [i][j][32].
// ---------------------------------------------------------------------------
__global__ __launch_bounds__(256) void k_conv1(const float* __restrict__ vol,
                                               const float* __restrict__ w1,
                                               const float* __restrict__ b1,
                                               float* __restrict__ out1) {
  __shared__ float wl[9 * CCH * CCH];  // 36 KB: [p][ci][o]
  int t = threadIdx.x;
  for (int e = t; e < 9 * CCH * CCH; e += 256) {
    int o = e & 31;
    int ci = (e >> 5) & 31;
    int p = e >> 10;           // 0..8
    int di = p / 3, dj = p % 3;
    wl[e] = w1[((o * CCH + ci) * 3 + di) * 3 + dj];
  }
  __syncthreads();

  int pix = blockIdx.x * 256 + t;
  int j = pix & 255, i = pix >> 8;

  float acc[CCH];
#pragma unroll
  for (int o = 0; o < CCH; ++o) acc[o] = b1[o];

#pragma unroll 1
  for (int p = 0; p < 9; ++p) {
    int di = p / 3, dj = p % 3;
    int ii = i + di - 2, jj = j + dj - 2;
    if (ii < 0 || jj < 0) continue;   // zero-padded region contributes nothing
    const float4* ip4 = (const float4*)(vol + ((size_t)(ii * NVOL + jj)) * CCH);
    const float* wp = &wl[p * CCH * CCH];
#pragma unroll
    for (int q = 0; q < 8; ++q) {
      float4 v = ip4[q];
      float iv[4] = {v.x, v.y, v.z, v.w};
#pragma unroll
      for (int cc = 0; cc < 4; ++cc) {
        const float4* wv4 = (const float4*)(wp + (4 * q + cc) * CCH);
#pragma unroll
        for (int o4 = 0; o4 < 8; ++o4) {
          float4 wv = wv4[o4];
          acc[o4 * 4 + 0] = fmaf(iv[cc], wv.x, acc[o4 * 4 + 0]);
          acc[o4 * 4 + 1] = fmaf(iv[cc], wv.y, acc[o4 * 4 + 1]);
          acc[o4 * 4 + 2] = fmaf(iv[cc], wv.z, acc[o4 * 4 + 2]);
          acc[o4 * 4 + 3] = fmaf(iv[cc], wv.w, acc[o4 * 4 + 3]);
        }
      }
    }
  }

  float4* op = (float4*)(out1 + (size_t)pix * CCH);
#pragma unroll
  for (int o4 = 0; o4 < 8; ++o4) {
    float4 v;
    v.x = 1.0f / (1.0f + expf(-acc[o4 * 4 + 0]));
    v.y = 1.0f / (1.0f + expf(-acc[o4 * 4 + 1]));
    v.z = 1.0f / (1.0f + expf(-acc[o4 * 4 + 2]));
    v.w = 1.0f / (1.0f + expf(-acc[o4 * 4 + 3]));
    op[o4] = v;
  }
}

// ---------------------------------------------------------------------------
// K4: 3x3 causal conv 32->1 + sigmoid.  out[i][j] row-major (matches ref).
// ---------------------------------------------------------------------------
__global__ __launch_bounds__(256) void k_conv2(const float* __restrict__ s1,
                                               const float* __restrict__ w2,
                                               const float* __restrict__ b2,
                                               float* __restrict__ out) {
  __shared__ float wl[9 * CCH];  // [p][ci]
  int t = threadIdx.x;
  for (int e = t; e < 9 * CCH; e += 256) {
    int ci = e & 31, p = e >> 5;
    int di = p / 3, dj = p % 3;
    wl[e] = w2[ci * 9 + di * 3 + dj];
  }
  __syncthreads();

  int pix = blockIdx.x * 256 + t;
  int j = pix & 255, i = pix >> 8;

  float acc = b2[0];
#pragma unroll 1
  for (int p = 0; p < 9; ++p) {
    int di = p / 3, dj = p % 3;
    int ii = i + di - 2, jj = j + dj - 2;
    if (ii < 0 || jj < 0) continue;
    const float4* ip4 = (const float4*)(s1 + ((size_t)(ii * NVOL + jj)) * CCH);
    const float4* wv4 = (const float4*)(&wl[p * CCH]);
#pragma unroll
    for (int q = 0; q < 8; ++q) {
      float4 v = ip4[q];
      float4 wv = wv4[q];
      acc = fmaf(v.x, wv.x, acc);
      acc = fmaf(v.y, wv.y, acc);
      acc = fmaf(v.z, wv.z, acc);
      acc = fmaf(v.w, wv.w, acc);
    }
  }
  out[pix] = 1.0f / (1.0f + expf(-acc));
}

// ---------------------------------------------------------------------------
extern "C" void kernel_launch(void* const* d_in, const int* in_sizes, int n_in,
                              void* d_out, int out_size, void* d_ws,
                              size_t ws_size, hipStream_t stream) {
  const float* x    = (const float*)d_in[0];  // [1,1,400,512]
  const float* wdet = (const float*)d_in[1];  // [32,1,1,11]
  const float* bdet = (const float*)d_in[2];  // [32]
  const float* w1   = (const float*)d_in[3];  // [32,32,3,3]
  const float* b1   = (const float*)d_in[4];  // [32]
  const float* w2   = (const float*)d_in[5];  // [1,32,3,3]
  const float* b2   = (const float*)d_in[6];  // [1]
  float* out = (float*)d_out;                 // [1,1,256,256]

  float* ws = (float*)d_ws;
  float* y    = ws;                       // [400][32][512]  = 26.2 MB
  float* vol  = y + A_ANG * CCH * DDET;   // [256][256][32]  =  8.4 MB
  float* sig1 = vol + NVOL * NVOL * CCH;  // [256][256][32]  =  8.4 MB

  k_detconv<<<dim3((A_ANG * CCH * DDET) / 256), dim3(256), 0, stream>>>(
      x, wdet, bdet, y);
  // vol is accumulated by atomics from 4 angle-chunk blocks per tile
  hipMemsetAsync(vol, 0, (size_t)NVOL * NVOL * CCH * sizeof(float), stream);
  k_backproj<<<dim3(256 * NCHUNK), dim3(256), 0, stream>>>(y, vol);
  k_conv1<<<dim3(256), dim3(256), 0, stream>>>(vol, w1, b1, sig1);
  k_conv2<<<dim3(256), dim3(256), 0, stream>>>(sig1, w2, b2, out);
}

// Round 2
// 232.020 us; speedup vs baseline: 2.5030x; 2.5030x over previous
//
#include <hip/hip_runtime.h>
#include <math.h>
#include <stdint.h>

#define A_ANG 400
#define DDET  512
#define NVOL  256
#define CCH   32
#define KSZ   11
#define PI_F  3.14159265358979323846f

#define NCHUNK 2
#define APC (A_ANG / NCHUNK)   // 200 angles per block
#define RING 8                 // LDS ring buffers (4KB each)
#define PD   6                 // prefetch distance (outstanding gll per wave)

typedef __attribute__((address_space(3))) uint32_t       lds_u32;
typedef const __attribute__((address_space(1))) uint32_t glb_u32;
#define GLL16(gp, lp) \
  __builtin_amdgcn_global_load_lds((glb_u32*)(gp), (lds_u32*)(lp), 16, 0, 0)

// ---------------------------------------------------------------------------
// K1: causal detector conv -> CHANNEL-LAST y2[a][d][c].
// y2[(a*512+d)*32+c] = b[c] + sum_k w[c][k]*x[a][d+k-10]
// wl stride 11 (odd) -> c*11 mod 32 bijective -> conflict-free LDS reads.
// ---------------------------------------------------------------------------
__global__ __launch_bounds__(256) void k_detconv(const float* __restrict__ x,
                                                 const float* __restrict__ wdet,
                                                 const float* __restrict__ bdet,
                                                 float* __restrict__ y2) {
  __shared__ float wl[CCH * KSZ];
  __shared__ float bl[CCH];
  int t = threadIdx.x;
  for (int e = t; e < CCH * KSZ; e += 256) wl[e] = wdet[e];
  if (t < CCH) bl[t] = bdet[t];
  __syncthreads();

  int idx = blockIdx.x * 256 + t;  // = a*16384 + d*32 + c
  int c = idx & 31;
  int d = (idx >> 5) & 511;
  int a = idx >> 14;
  const float* xr = x + a * DDET;
  float acc = bl[c];
#pragma unroll
  for (int k = 0; k < KSZ; ++k) {
    int dd = d + k - (KSZ - 1);
    float xv = (dd >= 0) ? xr[dd] : 0.0f;  // broadcast within wave (d uniform/32)
    acc = fmaf(wl[c * KSZ + k], xv, acc);
  }
  y2[idx] = acc;
}

// ---------------------------------------------------------------------------
// K2: backprojection v3 — deep-pipelined gll ring, counted vmcnt, raw barriers.
//   - y2 channel-last: staging one angle-window (32 cells x 32 ch = 4KB) is
//     ONE global_load_lds_dwordx4 per wave (wave w covers 1KB quarter).
//   - gll writes LDS linearly (rule #21) -> swizzle via pre-swizzled GLOBAL
//     source: 16B slot s holds logical (cell'=s>>3, q'=(s&7)^(cell'&7));
//     read side XORs the same involution -> <=3-way bank conflicts.
//   - ring of 8 buffers, PD=6 in flight, asm "s_waitcnt vmcnt(5)" + raw
//     s_barrier per angle: loads span barriers (no compiler vmcnt(0) drain).
//   - epilogue: acc -> LDS [c][pix] (stride 257, conflict-free transpose),
//     then atomicAdd with 64 CONSECUTIVE floats per instr (2 lines, not 64).
// Window interior proof: uc in [74.5,436.5] -> base in [58,420], base+31<512;
// off = k0-base in [4,28] (clamped 0..30 for safety).
// ---------------------------------------------------------------------------
__global__ __launch_bounds__(256) void k_backproj(const float* __restrict__ y2,
                                                  float* __restrict__ vol) {
  __shared__ __align__(16) float s_mem[32 * 257];  // ring (8192 fl) / out (8224 fl)
  __shared__ float s_sin[APC];
  __shared__ float s_cos[APC];

  int t = threadIdx.x;
  int tile = blockIdx.x & 255;
  int chunk = blockIdx.x >> 8;
  int a0 = chunk * APC;

  for (int a = t; a < APC; a += 256) {
    float ph = ((float)(a0 + a) + 0.5f) * (PI_F / (float)A_ANG);
    float sv, cv;
    sincosf(ph, &sv, &cv);
    s_sin[a] = sv;
    s_cos[a] = cv;
  }

  int bi = tile >> 4, bj = tile & 15;
  float Xp = 127.5f - (float)(bi * 16 + (t >> 4));
  float Yp = (float)(bj * 16 + (t & 15)) - 127.5f;
  float Xc = 120.0f - (float)(bi * 16);
  float Yc = (float)(bj * 16) - 120.0f;

  // gll source pre-swizzle: slot s = t -> cell'=t>>3, q'=(t&7)^((t>>3)&7)
  int cellp = t >> 3;
  int qp = (t & 7) ^ (cellp & 7);
  int lane_foff = cellp * CCH + qp * 4;   // float offset inside window row
  int wq = (t >> 6) << 8;                 // wave-uniform LDS quarter (floats)

  float acc[CCH];
#pragma unroll
  for (int c = 0; c < CCH; ++c) acc[c] = 0.0f;

  __syncthreads();  // tables ready (no loads in flight yet)

  const size_t rowstride = (size_t)DDET * CCH;  // 16384 floats per angle

  // prologue: fill pipeline with angles 0..PD-1
#pragma unroll
  for (int p = 0; p < PD; ++p) {
    float sp = s_sin[p], cp = s_cos[p];
    int base = (int)floorf(fmaf(Xc, sp, fmaf(Yc, cp, 255.5f))) - 16;
    const float* gsrc = y2 + (size_t)(a0 + p) * rowstride + base * CCH + lane_foff;
    float* ldst = s_mem + (p & (RING - 1)) * 1024 + wq;
    GLL16(gsrc, ldst);
  }
  asm volatile("s_waitcnt vmcnt(5)" ::: "memory");  // oldest (angle 0) landed
  __builtin_amdgcn_s_barrier();

  for (int k = 0; k < APC; ++k) {
    // issue prefetch for k+PD (clamped: uniform vmcnt count through the tail)
    {
      int an = k + PD;
      an = (an < APC) ? an : (APC - 1);
      float sp = s_sin[an], cp = s_cos[an];
      int base = (int)floorf(fmaf(Xc, sp, fmaf(Yc, cp, 255.5f))) - 16;
      const float* gsrc =
          y2 + (size_t)(a0 + an) * rowstride + base * CCH + lane_foff;
      float* ldst = s_mem + ((k + PD) & (RING - 1)) * 1024 + wq;
      GLL16(gsrc, ldst);
    }
    // compute angle k from ring[k&7] (completed before previous barrier)
    {
      float sp = s_sin[k], cp = s_cos[k];
      float uc = fmaf(Xc, sp, fmaf(Yc, cp, 255.5f));
      int base = (int)floorf(uc) - 16;
      float u = fmaf(Xp, sp, fmaf(Yp, cp, 255.5f));
      float k0f = floorf(u);
      float w = u - k0f;
      int off = (int)k0f - base;
      off = max(0, min(30, off));
      float w0 = 1.0f - w;
      const float* bufb = s_mem + (k & (RING - 1)) * 1024;
      int o0 = off * 32, x0 = (off & 7) * 4;
      int o1 = o0 + 32, x1 = ((off + 1) & 7) * 4;
#pragma unroll
      for (int q = 0; q < 8; ++q) {
        float4 g0 = *(const float4*)(bufb + o0 + ((q * 4) ^ x0));
        float4 g1 = *(const float4*)(bufb + o1 + ((q * 4) ^ x1));
        acc[4 * q + 0] = fmaf(g0.x, w0, acc[4 * q + 0]);
        acc[4 * q + 1] = fmaf(g0.y, w0, acc[4 * q + 1]);
        acc[4 * q + 2] = fmaf(g0.z, w0, acc[4 * q + 2]);
        acc[4 * q + 3] = fmaf(g0.w, w0, acc[4 * q + 3]);
        acc[4 * q + 0] = fmaf(g1.x, w, acc[4 * q + 0]);
        acc[4 * q + 1] = fmaf(g1.y, w, acc[4 * q + 1]);
        acc[4 * q + 2] = fmaf(g1.z, w, acc[4 * q + 2]);
        acc[4 * q + 3] = fmaf(g1.w, w, acc[4 * q + 3]);
      }
    }
    asm volatile("s_waitcnt vmcnt(5)" ::: "memory");  // angle k+1 landed
    __builtin_amdgcn_s_barrier();
  }

  // drain pipeline before reusing s_mem (tail glls still target ring slots)
  asm volatile("s_waitcnt vmcnt(0)" ::: "memory");
  __syncthreads();

  // epilogue: transpose through LDS, then line-coalesced atomics
  const float DPHI = PI_F / (float)A_ANG;
  int pix = t;  // (t>>4)*16 + (t&15) == t
#pragma unroll
  for (int c = 0; c < CCH; ++c) s_mem[c * 257 + pix] = acc[c] * DPHI;
  __syncthreads();

  size_t gbase = ((size_t)(bi * 16) * NVOL + (size_t)(bj * 16)) * CCH;
#pragma unroll
  for (int m = 0; m < 32; ++m) {
    int f = m * 256 + t;
    int c = f & 31;
    int p2 = f >> 5;  // pixel 0..255
    int jj = p2 & 15, ii = p2 >> 4;
    float v = s_mem[c * 257 + p2];
    atomicAdd(vol + gbase + ((size_t)ii * NVOL + jj) * CCH + c, v);
  }
}

// ---------------------------------------------------------------------------
// K3: 3x3 causal conv 32->32 + sigmoid.  in/out channel-last [i][j][32].
// ---------------------------------------------------------------------------
__global__ __launch_bounds__(256) void k_conv1(const float* __restrict__ vol,
                                               const float* __restrict__ w1,
                                               const float* __restrict__ b1,
                                               float* __restrict__ out1) {
  __shared__ float wl[9 * CCH * CCH];  // 36 KB: [p][ci][o]
  int t = threadIdx.x;
  for (int e = t; e < 9 * CCH * CCH; e += 256) {
    int o = e & 31;
    int ci = (e >> 5) & 31;
    int p = e >> 10;           // 0..8
    int di = p / 3, dj = p % 3;
    wl[e] = w1[((o * CCH + ci) * 3 + di) * 3 + dj];
  }
  __syncthreads();

  int pix = blockIdx.x * 256 + t;
  int j = pix & 255, i = pix >> 8;

  float acc[CCH];
#pragma unroll
  for (int o = 0; o < CCH; ++o) acc[o] = b1[o];

#pragma unroll 1
  for (int p = 0; p < 9; ++p) {
    int di = p / 3, dj = p % 3;
    int ii = i + di - 2, jj = j + dj - 2;
    if (ii < 0 || jj < 0) continue;   // zero-padded region contributes nothing
    const float4* ip4 = (const float4*)(vol + ((size_t)(ii * NVOL + jj)) * CCH);
    const float* wp = &wl[p * CCH * CCH];
#pragma unroll
    for (int q = 0; q < 8; ++q) {
      float4 v = ip4[q];
      float iv[4] = {v.x, v.y, v.z, v.w};
#pragma unroll
      for (int cc = 0; cc < 4; ++cc) {
        const float4* wv4 = (const float4*)(wp + (4 * q + cc) * CCH);
#pragma unroll
        for (int o4 = 0; o4 < 8; ++o4) {
          float4 wv = wv4[o4];
          acc[o4 * 4 + 0] = fmaf(iv[cc], wv.x, acc[o4 * 4 + 0]);
          acc[o4 * 4 + 1] = fmaf(iv[cc], wv.y, acc[o4 * 4 + 1]);
          acc[o4 * 4 + 2] = fmaf(iv[cc], wv.z, acc[o4 * 4 + 2]);
          acc[o4 * 4 + 3] = fmaf(iv[cc], wv.w, acc[o4 * 4 + 3]);
        }
      }
    }
  }

  float4* op = (float4*)(out1 + (size_t)pix * CCH);
#pragma unroll
  for (int o4 = 0; o4 < 8; ++o4) {
    float4 v;
    v.x = 1.0f / (1.0f + expf(-acc[o4 * 4 + 0]));
    v.y = 1.0f / (1.0f + expf(-acc[o4 * 4 + 1]));
    v.z = 1.0f / (1.0f + expf(-acc[o4 * 4 + 2]));
    v.w = 1.0f / (1.0f + expf(-acc[o4 * 4 + 3]));
    op[o4] = v;
  }
}

// ---------------------------------------------------------------------------
// K4: 3x3 causal conv 32->1 + sigmoid.  out[i][j] row-major (matches ref).
// ---------------------------------------------------------------------------
__global__ __launch_bounds__(256) void k_conv2(const float* __restrict__ s1,
                                               const float* __restrict__ w2,
                                               const float* __restrict__ b2,
                                               float* __restrict__ out) {
  __shared__ float wl[9 * CCH];  // [p][ci]
  int t = threadIdx.x;
  for (int e = t; e < 9 * CCH; e += 256) {
    int ci = e & 31, p = e >> 5;
    int di = p / 3, dj = p % 3;
    wl[e] = w2[ci * 9 + di * 3 + dj];
  }
  __syncthreads();

  int pix = blockIdx.x * 256 + t;
  int j = pix & 255, i = pix >> 8;

  float acc = b2[0];
#pragma unroll 1
  for (int p = 0; p < 9; ++p) {
    int di = p / 3, dj = p % 3;
    int ii = i + di - 2, jj = j + dj - 2;
    if (ii < 0 || jj < 0) continue;
    const float4* ip4 = (const float4*)(s1 + ((size_t)(ii * NVOL + jj)) * CCH);
    const float4* wv4 = (const float4*)(&wl[p * CCH]);
#pragma unroll
    for (int q = 0; q < 8; ++q) {
      float4 v = ip4[q];
      float4 wv = wv4[q];
      acc = fmaf(v.x, wv.x, acc);
      acc = fmaf(v.y, wv.y, acc);
      acc = fmaf(v.z, wv.z, acc);
      acc = fmaf(v.w, wv.w, acc);
    }
  }
  out[pix] = 1.0f / (1.0f + expf(-acc));
}

// ---------------------------------------------------------------------------
extern "C" void kernel_launch(void* const* d_in, const int* in_sizes, int n_in,
                              void* d_out, int out_size, void* d_ws,
                              size_t ws_size, hipStream_t stream) {
  const float* x    = (const float*)d_in[0];  // [1,1,400,512]
  const float* wdet = (const float*)d_in[1];  // [32,1,1,11]
  const float* bdet = (const float*)d_in[2];  // [32]
  const float* w1   = (const float*)d_in[3];  // [32,32,3,3]
  const float* b1   = (const float*)d_in[4];  // [32]
  const float* w2   = (const float*)d_in[5];  // [1,32,3,3]
  const float* b2   = (const float*)d_in[6];  // [1]
  float* out = (float*)d_out;                 // [1,1,256,256]

  float* ws = (float*)d_ws;
  float* y    = ws;                       // [400][512][32]  = 26.2 MB (ch-last)
  float* vol  = y + A_ANG * CCH * DDET;   // [256][256][32]  =  8.4 MB
  float* sig1 = vol + NVOL * NVOL * CCH;  // [256][256][32]  =  8.4 MB

  k_detconv<<<dim3((A_ANG * CCH * DDET) / 256), dim3(256), 0, stream>>>(
      x, wdet, bdet, y);
  // vol accumulated by 2 chunk-blocks per tile via line-coalesced atomics
  hipMemsetAsync(vol, 0, (size_t)NVOL * NVOL * CCH * sizeof(float), stream);
  k_backproj<<<dim3(256 * NCHUNK), dim3(256), 0, stream>>>(y, vol);
  k_conv1<<<dim3(256), dim3(256), 0, stream>>>(vol, w1, b1, sig1);
  k_conv2<<<dim3(256), dim3(256), 0, stream>>>(sig1, w2, b2, out);
}

// Round 3
// 206.312 us; speedup vs baseline: 2.8149x; 1.1246x over previous
//
#include <hip/hip_runtime.h>
#include <math.h>
#include <stdint.h>

#define A_ANG 400
#define DDET  512
#define NVOL  256
#define CCH   32
#define KSZ   11
#define PI_F  3.14159265358979323846f

#define NCHUNK 2
#define APC (A_ANG / NCHUNK)   // 200 angles per block
#define RING 8                 // LDS ring buffers
#define PD   6                 // prefetch distance in angles
#define GPA  5                 // global_load_lds(4B) instructions per angle
#define SLOTF 1088             // floats per ring slot = 32 cells * 34 (skew-17)

typedef __attribute__((address_space(3))) uint32_t       lds_u32;
typedef const __attribute__((address_space(1))) uint32_t glb_u32;
#define GLL4(gp, lp) \
  __builtin_amdgcn_global_load_lds((glb_u32*)(gp), (lds_u32*)(lp), 4, 0, 0)

// ---------------------------------------------------------------------------
// K1: causal detector conv -> CHANNEL-LAST y2[a][d][c].
// ---------------------------------------------------------------------------
__global__ __launch_bounds__(256) void k_detconv(const float* __restrict__ x,
                                                 const float* __restrict__ wdet,
                                                 const float* __restrict__ bdet,
                                                 float* __restrict__ y2) {
  __shared__ float wl[CCH * KSZ];
  __shared__ float bl[CCH];
  int t = threadIdx.x;
  for (int e = t; e < CCH * KSZ; e += 256) wl[e] = wdet[e];
  if (t < CCH) bl[t] = bdet[t];
  __syncthreads();

  int idx = blockIdx.x * 256 + t;  // = a*16384 + d*32 + c
  int c = idx & 31;
  int d = (idx >> 5) & 511;
  int a = idx >> 14;
  const float* xr = x + a * DDET;
  float acc = bl[c];
#pragma unroll
  for (int k = 0; k < KSZ; ++k) {
    int dd = d + k - (KSZ - 1);
    float xv = (dd >= 0) ? xr[dd] : 0.0f;
    acc = fmaf(wl[c * KSZ + k], xv, acc);
  }
  y2[idx] = acc;
}

// ---------------------------------------------------------------------------
// K2: backprojection v4 — skew-17 LDS layout, b64 reads, 2 angles/barrier.
//   - LDS slot: cell stride 34 floats (32 data + 2 pad).  ds_read_b64 at
//     float2 index off*17 + p2 -> bank-pair group (off+p2) mod 16:
//     16 groups, <=2-way (off vs off+16) = free (m136).  Kills the b128
//     3-bit-group conflicts (1.75e7 cyc in v3).
//   - staging: 5x global_load_lds width=4 per wave per angle (4B scatter
//     granularity needed by the 34-stride; source still coalesced).
//     Lane l of inst i writes slot float i*256 + t (i<4) / 1024+(t&63) (i=4,
//     all 4 waves duplicate unit 16 with identical data — benign).
//   - ring 8, PD=6 angles (30 loads in flight), vmcnt(20) = oldest 2 angles
//     landed; ONE barrier per TWO angles.  Slot audit: while computing
//     k,k+1 the in-flight writes target slots (k+2..k+7)&7 — disjoint.
//   - epilogue: acc -> LDS transpose (stride 257), line-coalesced atomics.
// ---------------------------------------------------------------------------
__global__ __launch_bounds__(256) void k_backproj(const float* __restrict__ y2,
                                                  float* __restrict__ vol) {
  __shared__ __align__(16) float s_mem[RING * SLOTF];  // 34816 B; reused by epilogue
  __shared__ float s_sin[APC];
  __shared__ float s_cos[APC];

  int t = threadIdx.x;
  int tile = blockIdx.x & 255;
  int chunk = blockIdx.x >> 8;
  int a0 = chunk * APC;

  for (int a = t; a < APC; a += 256) {
    float ph = ((float)(a0 + a) + 0.5f) * (PI_F / (float)A_ANG);
    float sv, cv;
    sincosf(ph, &sv, &cv);
    s_sin[a] = sv;
    s_cos[a] = cv;
  }

  int bi = tile >> 4, bj = tile & 15;
  float Xp = 127.5f - (float)(bi * 16 + (t >> 4));
  float Yp = (float)(bj * 16 + (t & 15)) - 127.5f;
  float Xc = 120.0f - (float)(bi * 16);
  float Yc = (float)(bj * 16) - 120.0f;

  // per-thread staging map (loop-invariant): inst i covers slot floats
  // p = i*256 + t (i<4) or 1024 + (t&63); slot float p belongs to
  // cell = p/34, r = p%34; global float = cell*32 + min(r,31) (pads dup c31).
  int wv = t >> 6;
  int goff[GPA];
  int ub[GPA];
#pragma unroll
  for (int i2 = 0; i2 < GPA; ++i2) {
    int p = (i2 < 4) ? (i2 * 256 + t) : (1024 + (t & 63));
    int cell = p / 34;
    int r = p - cell * 34;
    goff[i2] = cell * CCH + ((r < 32) ? r : 31);
    ub[i2] = ((i2 < 4) ? (i2 * 4 + wv) : 16) * 64;  // wave-uniform LDS base
  }

  float acc[CCH];
#pragma unroll
  for (int c = 0; c < CCH; ++c) acc[c] = 0.0f;

  __syncthreads();  // tables ready (no loads in flight yet)

  const size_t rowstride = (size_t)DDET * CCH;

  auto issue = [&](int an, int slot) {
    float sp = s_sin[an], cp = s_cos[an];
    int base = (int)floorf(fmaf(Xc, sp, fmaf(Yc, cp, 255.5f))) - 16;
    const float* grow = y2 + (size_t)(a0 + an) * rowstride + base * CCH;
    float* sl = s_mem + slot * SLOTF;
#pragma unroll
    for (int i2 = 0; i2 < GPA; ++i2) GLL4(grow + goff[i2], sl + ub[i2]);
  };

  auto compute = [&](int k) {
    float sp = s_sin[k], cp = s_cos[k];
    float uc = fmaf(Xc, sp, fmaf(Yc, cp, 255.5f));
    int base = (int)floorf(uc) - 16;
    float u = fmaf(Xp, sp, fmaf(Yp, cp, 255.5f));
    float k0f = floorf(u);
    float wgt = u - k0f;
    int off = (int)k0f - base;
    off = max(0, min(30, off));  // provably in [4,28]
    float w0 = 1.0f - wgt;
    const float* bp = s_mem + (k & (RING - 1)) * SLOTF + off * 34;
#pragma unroll
    for (int p2 = 0; p2 < 16; ++p2) {
      float2 g0 = *(const float2*)(bp + 2 * p2);       // cells off, ch 2p2..+1
      float2 g1 = *(const float2*)(bp + 34 + 2 * p2);  // cell off+1
      acc[2 * p2 + 0] = fmaf(g0.x, w0, acc[2 * p2 + 0]);
      acc[2 * p2 + 1] = fmaf(g0.y, w0, acc[2 * p2 + 1]);
      acc[2 * p2 + 0] = fmaf(g1.x, wgt, acc[2 * p2 + 0]);
      acc[2 * p2 + 1] = fmaf(g1.y, wgt, acc[2 * p2 + 1]);
    }
  };

  // prologue: fill pipeline with angles 0..PD-1 (30 loads in flight)
#pragma unroll
  for (int p = 0; p < PD; ++p) issue(p, p & (RING - 1));
  asm volatile("s_waitcnt vmcnt(20)" ::: "memory");  // angles 0,1 landed
  __builtin_amdgcn_s_barrier();

  for (int k = 0; k < APC; k += 2) {
    compute(k);
    compute(k + 1);
    int a1 = k + PD;     a1 = (a1 < APC) ? a1 : (APC - 1);
    int a2 = k + PD + 1; a2 = (a2 < APC) ? a2 : (APC - 1);
    issue(a1, (k + PD) & (RING - 1));
    issue(a2, (k + PD + 1) & (RING - 1));
    asm volatile("s_waitcnt vmcnt(20)" ::: "memory");  // k+2, k+3 landed
    __builtin_amdgcn_s_barrier();
  }

  // drain before reusing s_mem (tail glls still target ring slots)
  asm volatile("s_waitcnt vmcnt(0)" ::: "memory");
  __syncthreads();

  // epilogue: transpose through LDS, then line-coalesced atomics
  const float DPHI = PI_F / (float)A_ANG;
#pragma unroll
  for (int c = 0; c < CCH; ++c) s_mem[c * 257 + t] = acc[c] * DPHI;
  __syncthreads();

  size_t gbase = ((size_t)(bi * 16) * NVOL + (size_t)(bj * 16)) * CCH;
#pragma unroll
  for (int m = 0; m < 32; ++m) {
    int f = m * 256 + t;
    int c = f & 31;
    int p2 = f >> 5;  // pixel 0..255
    int jj = p2 & 15, ii = p2 >> 4;
    float v = s_mem[c * 257 + p2];
    atomicAdd(vol + gbase + ((size_t)ii * NVOL + jj) * CCH + c, v);
  }
}

// ---------------------------------------------------------------------------
// K3: 3x3 causal conv 32->32 + sigmoid.  in/out channel-last [i][j][32].
// ---------------------------------------------------------------------------
__global__ __launch_bounds__(256) void k_conv1(const float* __restrict__ vol,
                                               const float* __restrict__ w1,
                                               const float* __restrict__ b1,
                                               float* __restrict__ out1) {
  __shared__ float wl[9 * CCH * CCH];  // 36 KB: [p][ci][o]
  int t = threadIdx.x;
  for (int e = t; e < 9 * CCH * CCH; e += 256) {
    int o = e & 31;
    int ci = (e >> 5) & 31;
    int p = e >> 10;           // 0..8
    int di = p / 3, dj = p % 3;
    wl[e] = w1[((o * CCH + ci) * 3 + di) * 3 + dj];
  }
  __syncthreads();

  int pix = blockIdx.x * 256 + t;
  int j = pix & 255, i = pix >> 8;

  float acc[CCH];
#pragma unroll
  for (int o = 0; o < CCH; ++o) acc[o] = b1[o];

#pragma unroll 1
  for (int p = 0; p < 9; ++p) {
    int di = p / 3, dj = p % 3;
    int ii = i + di - 2, jj = j + dj - 2;
    if (ii < 0 || jj < 0) continue;   // zero-padded region contributes nothing
    const float4* ip4 = (const float4*)(vol + ((size_t)(ii * NVOL + jj)) * CCH);
    const float* wp = &wl[p * CCH * CCH];
#pragma unroll
    for (int q = 0; q < 8; ++q) {
      float4 v = ip4[q];
      float iv[4] = {v.x, v.y, v.z, v.w};
#pragma unroll
      for (int cc = 0; cc < 4; ++cc) {
        const float4* wv4 = (const float4*)(wp + (4 * q + cc) * CCH);
#pragma unroll
        for (int o4 = 0; o4 < 8; ++o4) {
          float4 wv = wv4[o4];
          acc[o4 * 4 + 0] = fmaf(iv[cc], wv.x, acc[o4 * 4 + 0]);
          acc[o4 * 4 + 1] = fmaf(iv[cc], wv.y, acc[o4 * 4 + 1]);
          acc[o4 * 4 + 2] = fmaf(iv[cc], wv.z, acc[o4 * 4 + 2]);
          acc[o4 * 4 + 3] = fmaf(iv[cc], wv.w, acc[o4 * 4 + 3]);
        }
      }
    }
  }

  float4* op = (float4*)(out1 + (size_t)pix * CCH);
#pragma unroll
  for (int o4 = 0; o4 < 8; ++o4) {
    float4 v;
    v.x = 1.0f / (1.0f + expf(-acc[o4 * 4 + 0]));
    v.y = 1.0f / (1.0f + expf(-acc[o4 * 4 + 1]));
    v.z = 1.0f / (1.0f + expf(-acc[o4 * 4 + 2]));
    v.w = 1.0f / (1.0f + expf(-acc[o4 * 4 + 3]));
    op[o4] = v;
  }
}

// ---------------------------------------------------------------------------
// K4: 3x3 causal conv 32->1 + sigmoid.  out[i][j] row-major (matches ref).
// ---------------------------------------------------------------------------
__global__ __launch_bounds__(256) void k_conv2(const float* __restrict__ s1,
                                               const float* __restrict__ w2,
                                               const float* __restrict__ b2,
                                               float* __restrict__ out) {
  __shared__ float wl[9 * CCH];  // [p][ci]
  int t = threadIdx.x;
  for (int e = t; e < 9 * CCH; e += 256) {
    int ci = e & 31, p = e >> 5;
    int di = p / 3, dj = p % 3;
    wl[e] = w2[ci * 9 + di * 3 + dj];
  }
  __syncthreads();

  int pix = blockIdx.x * 256 + t;
  int j = pix & 255, i = pix >> 8;

  float acc = b2[0];
#pragma unroll 1
  for (int p = 0; p < 9; ++p) {
    int di = p / 3, dj = p % 3;
    int ii = i + di - 2, jj = j + dj - 2;
    if (ii < 0 || jj < 0) continue;
    const float4* ip4 = (const float4*)(s1 + ((size_t)(ii * NVOL + jj)) * CCH);
    const float4* wv4 = (const float4*)(&wl[p * CCH]);
#pragma unroll
    for (int q = 0; q < 8; ++q) {
      float4 v = ip4[q];
      float4 wv = wv4[q];
      acc = fmaf(v.x, wv.x, acc);
      acc = fmaf(v.y, wv.y, acc);
      acc = fmaf(v.z, wv.z, acc);
      acc = fmaf(v.w, wv.w, acc);
    }
  }
  out[pix] = 1.0f / (1.0f + expf(-acc));
}

// ---------------------------------------------------------------------------
extern "C" void kernel_launch(void* const* d_in, const int* in_sizes, int n_in,
                              void* d_out, int out_size, void* d_ws,
                              size_t ws_size, hipStream_t stream) {
  const float* x    = (const float*)d_in[0];  // [1,1,400,512]
  const float* wdet = (const float*)d_in[1];  // [32,1,1,11]
  const float* bdet = (const float*)d_in[2];  // [32]
  const float* w1   = (const float*)d_in[3];  // [32,32,3,3]
  const float* b1   = (const float*)d_in[4];  // [32]
  const float* w2   = (const float*)d_in[5];  // [1,32,3,3]
  const float* b2   = (const float*)d_in[6];  // [1]
  float* out = (float*)d_out;                 // [1,1,256,256]

  float* ws = (float*)d_ws;
  float* y    = ws;                       // [400][512][32]  = 26.2 MB (ch-last)
  float* vol  = y + A_ANG * CCH * DDET;   // [256][256][32]  =  8.4 MB
  float* sig1 = vol + NVOL * NVOL * CCH;  // [256][256][32]  =  8.4 MB

  k_detconv<<<dim3((A_ANG * CCH * DDET) / 256), dim3(256), 0, stream>>>(
      x, wdet, bdet, y);
  // vol accumulated by 2 chunk-blocks per tile via line-coalesced atomics
  hipMemsetAsync(vol, 0, (size_t)NVOL * NVOL * CCH * sizeof(float), stream);
  k_backproj<<<dim3(256 * NCHUNK), dim3(256), 0, stream>>>(y, vol);
  k_conv1<<<dim3(256), dim3(256), 0, stream>>>(vol, w1, b1, sig1);
  k_conv2<<<dim3(256), dim3(256), 0, stream>>>(sig1, w2, b2, out);
}